// Round 1
// baseline (785.621 us; speedup 1.0000x reference)
//
#include <hip/hip_runtime.h>
#include <hip/hip_bf16.h>

using u16 = unsigned short;
using u32 = unsigned int;
using short8  = __attribute__((ext_vector_type(8))) short;
using floatx4 = __attribute__((ext_vector_type(4))) float;

#define TT 2048
#define CC 1024
#define HH 16
#define DD 64
#define BBATCH 2
#define MM (BBATCH*TT)   // 4096

__device__ __forceinline__ u16 f2bf(float f) {
    u32 u = __float_as_uint(f);
    u += 0x7fffu + ((u >> 16) & 1u);   // RNE
    return (u16)(u >> 16);
}
__device__ __forceinline__ float bf2f(u16 s) {
    return __uint_as_float(((u32)s) << 16);
}

// ---------------- cast fp32 -> bf16 ----------------
__global__ __launch_bounds__(256) void cast_kernel(const float* __restrict__ in,
                                                   u16* __restrict__ out, int n4) {
    int i = blockIdx.x * blockDim.x + threadIdx.x;
    if (i >= n4) return;
    float4 v = ((const float4*)in)[i];
    u16 r[4];
    r[0] = f2bf(v.x); r[1] = f2bf(v.y); r[2] = f2bf(v.z); r[3] = f2bf(v.w);
    ((ushort4*)out)[i] = *(ushort4*)r;
}

// ---------------- bf16 MFMA GEMM: y = A @ W^T + b ----------------
// A [M][K] bf16 row-major, W [N][K] bf16 row-major (torch Linear weight).
// OUT_MODE 0: write bf16 to [B,H,T,D]; OUT_MODE 1: write fp32 to [M][N].
template <int OUT_MODE>
__device__ __forceinline__ void gemm_core(const u16* __restrict__ A, const u16* __restrict__ W,
                                          const float* __restrict__ bias, void* __restrict__ outp)
{
    __shared__ u16 As[128*32];
    __shared__ u16 Bs[128*32];
    const int K = CC;
    int tid = threadIdx.x;
    int m0 = blockIdx.y * 128;
    int n0 = blockIdx.x * 128;
    int ar = tid >> 2;          // 0..63 (row within tile for staging)
    int ac = (tid & 3) * 8;     // k-col within 32-wide tile
    int lane = tid & 63;
    int w  = tid >> 6;
    int wm = (w >> 1) * 64;
    int wn = (w & 1) * 64;
    int lm = lane & 15;
    int lq = lane >> 4;

    floatx4 acc[4][4];
#pragma unroll
    for (int i = 0; i < 4; ++i)
#pragma unroll
        for (int j = 0; j < 4; ++j)
            acc[i][j] = (floatx4){0.f, 0.f, 0.f, 0.f};

    const u16* a0 = A + (size_t)(m0 + ar) * K + ac;
    const u16* a1 = A + (size_t)(m0 + ar + 64) * K + ac;
    const u16* w0 = W + (size_t)(n0 + ar) * K + ac;
    const u16* w1 = W + (size_t)(n0 + ar + 64) * K + ac;

    for (int k0 = 0; k0 < K; k0 += 32) {
        __syncthreads();
        *(uint4*)(As + ar*32 + ac)      = *(const uint4*)(a0 + k0);
        *(uint4*)(As + (ar+64)*32 + ac) = *(const uint4*)(a1 + k0);
        *(uint4*)(Bs + ar*32 + ac)      = *(const uint4*)(w0 + k0);
        *(uint4*)(Bs + (ar+64)*32 + ac) = *(const uint4*)(w1 + k0);
        __syncthreads();
        short8 af[4], bfr[4];
#pragma unroll
        for (int t = 0; t < 4; ++t) {
            af[t]  = *(const short8*)(As + (wm + t*16 + lm)*32 + lq*8);
            bfr[t] = *(const short8*)(Bs + (wn + t*16 + lm)*32 + lq*8);
        }
#pragma unroll
        for (int i = 0; i < 4; ++i)
#pragma unroll
            for (int j = 0; j < 4; ++j)
                acc[i][j] = __builtin_amdgcn_mfma_f32_16x16x32_bf16(af[i], bfr[j], acc[i][j], 0, 0, 0);
    }

#pragma unroll
    for (int j = 0; j < 4; ++j) {
        int col = n0 + wn + j*16 + lm;
        float bv = bias[col];
#pragma unroll
        for (int i = 0; i < 4; ++i) {
#pragma unroll
            for (int r = 0; r < 4; ++r) {
                int row = m0 + wm + i*16 + lq*4 + r;
                float val = acc[i][j][r] + bv;
                if (OUT_MODE == 0) {
                    int b_ = row >> 11, t_ = row & (TT-1);
                    int h_ = col >> 6,  d_ = col & 63;
                    ((u16*)outp)[(((size_t)(b_*HH + h_) * TT + t_) * DD) + d_] = f2bf(val);
                } else {
                    ((float*)outp)[(size_t)row * CC + col] = val;
                }
            }
        }
    }
}

__global__ __launch_bounds__(256) void qkv_gemm(const u16* __restrict__ xb,
    const u16* __restrict__ wq, const u16* __restrict__ wk, const u16* __restrict__ wv,
    const float* __restrict__ bq, const float* __restrict__ bk, const float* __restrict__ bv,
    u16* __restrict__ q, u16* __restrict__ k, u16* __restrict__ v)
{
    int z = blockIdx.z;
    const u16* W = (z == 0) ? wq : (z == 1) ? wk : wv;
    const float* bias = (z == 0) ? bq : (z == 1) ? bk : bv;
    u16* outp = (z == 0) ? q : (z == 1) ? k : v;
    gemm_core<0>(xb, W, bias, outp);
}

__global__ __launch_bounds__(256) void o_gemm(const u16* __restrict__ a, const u16* __restrict__ w,
                                              const float* __restrict__ bias, float* __restrict__ outp)
{
    gemm_core<1>(a, w, bias, outp);
}

// ---------------- flash attention (fp32 vector), causal ----------------
// q,k,v: [B*H][T][D] bf16.  attn out: [B][T][C] bf16.
__global__ __launch_bounds__(256) void attn_fa(const u16* __restrict__ qg, const u16* __restrict__ kg,
                                               const u16* __restrict__ vg, u16* __restrict__ attn)
{
    int qt = blockIdx.x;       // 0..31 q-tile
    int bh = blockIdx.y;       // 0..31
    int tid = threadIdx.x;
    int b_ = bh >> 4, h_ = bh & 15;

    __shared__ float Qs[64][68];
    __shared__ float Ks[64][68];
    __shared__ u16   Vs[64][64];
    __shared__ float Ss[64][68];
    __shared__ float mrow[64], lrow[64], arow[64];
    __shared__ float mpart[64][4], spart[64][4];

    size_t base = (size_t)bh * TT * DD;
    int q0 = qt * 64;

    // stage Q tile (scaled by 1/sqrt(D) = 0.125)
#pragma unroll
    for (int it = 0; it < 2; ++it) {
        int e = tid + it*256;
        int r = e >> 3, c = (e & 7) * 8;
        uint4 raw = *(const uint4*)(qg + base + (size_t)(q0 + r) * DD + c);
        u16 us[8]; *(uint4*)us = raw;
#pragma unroll
        for (int j = 0; j < 8; ++j) Qs[r][c+j] = bf2f(us[j]) * 0.125f;
    }
    if (tid < 64) { mrow[tid] = -1e38f; lrow[tid] = 0.f; }

    int ty = tid >> 4, tx = tid & 15;
    int r0 = ty*4, c0 = tx*4;
    float o[4][4] = {};

    for (int kt = 0; kt <= qt; ++kt) {
        __syncthreads();
        // stage K (fp32) and V (bf16)
#pragma unroll
        for (int it = 0; it < 2; ++it) {
            int e = tid + it*256;
            int r = e >> 3, c = (e & 7) * 8;
            size_t g = base + (size_t)(kt*64 + r) * DD + c;
            uint4 kraw = *(const uint4*)(kg + g);
            u16 us[8]; *(uint4*)us = kraw;
#pragma unroll
            for (int j = 0; j < 8; ++j) Ks[r][c+j] = bf2f(us[j]);
            *(uint4*)&Vs[r][c] = *(const uint4*)(vg + g);
        }
        __syncthreads();

        // S = Q K^T (Q pre-scaled)
        float s[4][4] = {};
        for (int d = 0; d < 64; d += 4) {
            float4 qv[4], kv[4];
#pragma unroll
            for (int i = 0; i < 4; ++i) qv[i] = *(const float4*)&Qs[r0+i][d];
#pragma unroll
            for (int j = 0; j < 4; ++j) kv[j] = *(const float4*)&Ks[c0+j][d];
#pragma unroll
            for (int i = 0; i < 4; ++i)
#pragma unroll
                for (int j = 0; j < 4; ++j)
                    s[i][j] += qv[i].x*kv[j].x + qv[i].y*kv[j].y + qv[i].z*kv[j].z + qv[i].w*kv[j].w;
        }
        if (kt == qt) {
#pragma unroll
            for (int i = 0; i < 4; ++i)
#pragma unroll
                for (int j = 0; j < 4; ++j)
                    if (c0+j > r0+i) s[i][j] = -1e30f;
        }
#pragma unroll
        for (int i = 0; i < 4; ++i)
#pragma unroll
            for (int j = 0; j < 4; ++j)
                Ss[r0+i][c0+j] = s[i][j];
        __syncthreads();

        // online softmax, 4 threads per row
        int sr = tid >> 2, sq = tid & 3;
        {
            float mt = -1e38f;
#pragma unroll
            for (int c = 0; c < 16; ++c) mt = fmaxf(mt, Ss[sr][sq*16 + c]);
            mpart[sr][sq] = mt;
        }
        __syncthreads();
        float newm = fmaxf(fmaxf(fmaxf(mpart[sr][0], mpart[sr][1]),
                                 fmaxf(mpart[sr][2], mpart[sr][3])), mrow[sr]);
        {
            float sum = 0.f;
#pragma unroll
            for (int c = 0; c < 16; ++c) {
                float p = __expf(Ss[sr][sq*16 + c] - newm);
                Ss[sr][sq*16 + c] = p;
                sum += p;
            }
            spart[sr][sq] = sum;
        }
        __syncthreads();
        if (sq == 0) {
            float al = __expf(mrow[sr] - newm);
            lrow[sr] = lrow[sr]*al + spart[sr][0]+spart[sr][1]+spart[sr][2]+spart[sr][3];
            mrow[sr] = newm;
            arow[sr] = al;
        }
        __syncthreads();

        // O = O*alpha + P V
        float al4[4];
#pragma unroll
        for (int i = 0; i < 4; ++i) al4[i] = arow[r0+i];
#pragma unroll
        for (int i = 0; i < 4; ++i)
#pragma unroll
            for (int j = 0; j < 4; ++j) o[i][j] *= al4[i];

        for (int jj = 0; jj < 64; jj += 4) {
            float p4[4][4];
#pragma unroll
            for (int i = 0; i < 4; ++i) {
                float4 pv = *(const float4*)&Ss[r0+i][jj];
                p4[i][0] = pv.x; p4[i][1] = pv.y; p4[i][2] = pv.z; p4[i][3] = pv.w;
            }
#pragma unroll
            for (int t = 0; t < 4; ++t) {
                ushort4 vr = *(const ushort4*)&Vs[jj+t][c0];
                float v0 = bf2f(vr.x), v1 = bf2f(vr.y), v2 = bf2f(vr.z), v3 = bf2f(vr.w);
#pragma unroll
                for (int i = 0; i < 4; ++i) {
                    o[i][0] += p4[i][t] * v0;
                    o[i][1] += p4[i][t] * v1;
                    o[i][2] += p4[i][t] * v2;
                    o[i][3] += p4[i][t] * v3;
                }
            }
        }
    }

    // finalize: divide by l, write [B,T,C] bf16
#pragma unroll
    for (int i = 0; i < 4; ++i) {
        float inv = 1.f / lrow[r0+i];
        size_t rowbase = ((size_t)(b_*TT + q0 + r0 + i)) * CC + h_*DD + c0;
        u16 rr[4];
#pragma unroll
        for (int j = 0; j < 4; ++j) rr[j] = f2bf(o[i][j] * inv);
        *(ushort4*)(attn + rowbase) = *(ushort4*)rr;
    }
}

extern "C" void kernel_launch(void* const* d_in, const int* in_sizes, int n_in,
                              void* d_out, int out_size, void* d_ws, size_t ws_size,
                              hipStream_t stream)
{
    const float* x  = (const float*)d_in[0];
    const float* Wq = (const float*)d_in[1];
    const float* bq = (const float*)d_in[2];
    const float* Wk = (const float*)d_in[3];
    const float* bk = (const float*)d_in[4];
    const float* Wv = (const float*)d_in[5];
    const float* bv = (const float*)d_in[6];
    const float* Wo = (const float*)d_in[7];
    const float* bo = (const float*)d_in[8];
    float* out = (float*)d_out;

    char* ws = (char*)d_ws;
    u16* xb   = (u16*)(ws);                      // 8 MB
    u16* wqb  = (u16*)(ws + (size_t)( 8<<20));   // 2 MB each
    u16* wkb  = (u16*)(ws + (size_t)(10<<20));
    u16* wvb  = (u16*)(ws + (size_t)(12<<20));
    u16* wob  = (u16*)(ws + (size_t)(14<<20));
    u16* q    = (u16*)(ws + (size_t)(16<<20));   // 8 MB each, [B,H,T,D]
    u16* k    = (u16*)(ws + (size_t)(24<<20));
    u16* v    = (u16*)(ws + (size_t)(32<<20));
    u16* attn = (u16*)(ws + (size_t)(40<<20));   // 8 MB, [B,T,C]

    cast_kernel<<<dim3(MM*CC/4/256), dim3(256), 0, stream>>>(x,  xb,  MM*CC/4);
    cast_kernel<<<dim3(CC*CC/4/256), dim3(256), 0, stream>>>(Wq, wqb, CC*CC/4);
    cast_kernel<<<dim3(CC*CC/4/256), dim3(256), 0, stream>>>(Wk, wkb, CC*CC/4);
    cast_kernel<<<dim3(CC*CC/4/256), dim3(256), 0, stream>>>(Wv, wvb, CC*CC/4);
    cast_kernel<<<dim3(CC*CC/4/256), dim3(256), 0, stream>>>(Wo, wob, CC*CC/4);

    dim3 gq(CC/128, MM/128, 3);
    qkv_gemm<<<gq, dim3(256), 0, stream>>>(xb, wqb, wkb, wvb, bq, bk, bv, q, k, v);

    dim3 ga(TT/64, BBATCH*HH);
    attn_fa<<<ga, dim3(256), 0, stream>>>(q, k, v, attn);

    dim3 go(CC/128, MM/128);
    o_gemm<<<go, dim3(256), 0, stream>>>(attn, wob, bo, out);
}

// Round 2
// 290.051 us; speedup vs baseline: 2.7086x; 2.7086x over previous
//
#include <hip/hip_runtime.h>
#include <hip/hip_bf16.h>

using u16 = unsigned short;
using u32 = unsigned int;
using short8  = __attribute__((ext_vector_type(8))) short;
using floatx4 = __attribute__((ext_vector_type(4))) float;

#define TT 2048
#define CC 1024
#define HH 16
#define DD 64
#define BBATCH 2
#define MM (BBATCH*TT)   // 4096

__device__ __forceinline__ u16 f2bf(float f) {
    u32 u = __float_as_uint(f);
    u += 0x7fffu + ((u >> 16) & 1u);   // RNE
    return (u16)(u >> 16);
}
__device__ __forceinline__ float bf2f(u16 s) {
    return __uint_as_float(((u32)s) << 16);
}

// max across 16-lane DPP row (lanes 0-15, 16-31, ...). All lanes get result.
__device__ __forceinline__ float dpp_rowmax16(float x) {
    float o = x;
    int t;
    t = __builtin_amdgcn_update_dpp(0, __float_as_int(o), 0xB1, 0xf, 0xf, true);  // quad_perm(1,0,3,2)
    o = fmaxf(o, __int_as_float(t));
    t = __builtin_amdgcn_update_dpp(0, __float_as_int(o), 0x4E, 0xf, 0xf, true);  // quad_perm(2,3,0,1)
    o = fmaxf(o, __int_as_float(t));
    t = __builtin_amdgcn_update_dpp(0, __float_as_int(o), 0x141, 0xf, 0xf, true); // row_half_mirror
    o = fmaxf(o, __int_as_float(t));
    t = __builtin_amdgcn_update_dpp(0, __float_as_int(o), 0x140, 0xf, 0xf, true); // row_mirror
    o = fmaxf(o, __int_as_float(t));
    return o;
}

// ---------------- cast fp32 -> bf16 ----------------
__global__ __launch_bounds__(256) void cast_kernel(const float* __restrict__ in,
                                                   u16* __restrict__ out, int n4) {
    int i = blockIdx.x * blockDim.x + threadIdx.x;
    if (i >= n4) return;
    float4 v = ((const float4*)in)[i];
    u16 r[4];
    r[0] = f2bf(v.x); r[1] = f2bf(v.y); r[2] = f2bf(v.z); r[3] = f2bf(v.w);
    ((ushort4*)out)[i] = *(ushort4*)r;
}

// ---------------- V transpose: [BH][T][D] -> [BH][D][T] ----------------
__global__ __launch_bounds__(256) void transpose_v(const u16* __restrict__ v, u16* __restrict__ vt) {
    __shared__ u16 tile[64][72];
    int bh = blockIdx.y;
    int t0 = blockIdx.x * 64;
    int r = threadIdx.x >> 2;          // 0..63
    int c = (threadIdx.x & 3) * 16;    // 0,16,32,48
    const u16* src = v + ((size_t)bh * TT + t0 + r) * DD + c;
    *(uint4*)&tile[r][c]     = *(const uint4*)src;
    *(uint4*)&tile[r][c + 8] = *(const uint4*)(src + 8);
    __syncthreads();
    // out row d = r, cols t0+c .. t0+c+15
    u16 tmp[16];
#pragma unroll
    for (int j = 0; j < 16; ++j) tmp[j] = tile[c + j][r];
    u16* dst = vt + ((size_t)bh * DD + r) * TT + t0 + c;
    *(uint4*)dst       = *(uint4*)&tmp[0];
    *(uint4*)(dst + 8) = *(uint4*)&tmp[8];
}

// ---------------- bf16 MFMA GEMM: y = A @ W^T + b ----------------
template <int OUT_MODE>
__device__ __forceinline__ void gemm_core(const u16* __restrict__ A, const u16* __restrict__ W,
                                          const float* __restrict__ bias, void* __restrict__ outp)
{
    __shared__ u16 As[128*32];
    __shared__ u16 Bs[128*32];
    const int K = CC;
    int tid = threadIdx.x;
    int m0 = blockIdx.y * 128;
    int n0 = blockIdx.x * 128;
    int ar = tid >> 2;
    int ac = (tid & 3) * 8;
    int lane = tid & 63;
    int w  = tid >> 6;
    int wm = (w >> 1) * 64;
    int wn = (w & 1) * 64;
    int lm = lane & 15;
    int lq = lane >> 4;

    floatx4 acc[4][4];
#pragma unroll
    for (int i = 0; i < 4; ++i)
#pragma unroll
        for (int j = 0; j < 4; ++j)
            acc[i][j] = (floatx4){0.f, 0.f, 0.f, 0.f};

    const u16* a0 = A + (size_t)(m0 + ar) * K + ac;
    const u16* a1 = A + (size_t)(m0 + ar + 64) * K + ac;
    const u16* w0 = W + (size_t)(n0 + ar) * K + ac;
    const u16* w1 = W + (size_t)(n0 + ar + 64) * K + ac;

    for (int k0 = 0; k0 < K; k0 += 32) {
        __syncthreads();
        *(uint4*)(As + ar*32 + ac)      = *(const uint4*)(a0 + k0);
        *(uint4*)(As + (ar+64)*32 + ac) = *(const uint4*)(a1 + k0);
        *(uint4*)(Bs + ar*32 + ac)      = *(const uint4*)(w0 + k0);
        *(uint4*)(Bs + (ar+64)*32 + ac) = *(const uint4*)(w1 + k0);
        __syncthreads();
        short8 af[4], bfr[4];
#pragma unroll
        for (int t = 0; t < 4; ++t) {
            af[t]  = *(const short8*)(As + (wm + t*16 + lm)*32 + lq*8);
            bfr[t] = *(const short8*)(Bs + (wn + t*16 + lm)*32 + lq*8);
        }
#pragma unroll
        for (int i = 0; i < 4; ++i)
#pragma unroll
            for (int j = 0; j < 4; ++j)
                acc[i][j] = __builtin_amdgcn_mfma_f32_16x16x32_bf16(af[i], bfr[j], acc[i][j], 0, 0, 0);
    }

#pragma unroll
    for (int j = 0; j < 4; ++j) {
        int col = n0 + wn + j*16 + lm;
        float bv = bias[col];
#pragma unroll
        for (int i = 0; i < 4; ++i) {
#pragma unroll
            for (int r = 0; r < 4; ++r) {
                int row = m0 + wm + i*16 + lq*4 + r;
                float val = acc[i][j][r] + bv;
                if (OUT_MODE == 0) {
                    int b_ = row >> 11, t_ = row & (TT-1);
                    int h_ = col >> 6,  d_ = col & 63;
                    ((u16*)outp)[(((size_t)(b_*HH + h_) * TT + t_) * DD) + d_] = f2bf(val);
                } else {
                    ((float*)outp)[(size_t)row * CC + col] = val;
                }
            }
        }
    }
}

__global__ __launch_bounds__(256) void qkv_gemm(const u16* __restrict__ xb,
    const u16* __restrict__ wq, const u16* __restrict__ wk, const u16* __restrict__ wv,
    const float* __restrict__ bq, const float* __restrict__ bk, const float* __restrict__ bv,
    u16* __restrict__ q, u16* __restrict__ k, u16* __restrict__ v)
{
    int z = blockIdx.z;
    const u16* W = (z == 0) ? wq : (z == 1) ? wk : wv;
    const float* bias = (z == 0) ? bq : (z == 1) ? bk : bv;
    u16* outp = (z == 0) ? q : (z == 1) ? k : v;
    gemm_core<0>(xb, W, bias, outp);
}

__global__ __launch_bounds__(256) void o_gemm(const u16* __restrict__ a, const u16* __restrict__ w,
                                              const float* __restrict__ bias, float* __restrict__ outp)
{
    gemm_core<1>(a, w, bias, outp);
}

// ---------------- MFMA flash attention, causal ----------------
// q,k: [B*H][T][D] bf16.  vt: [B*H][D][T] bf16.  attnb: [B][T][C] bf16.
// Br=128 (4 waves x 32 rows), Bc=64.
__global__ __launch_bounds__(256) void attn_mfma(const u16* __restrict__ qg, const u16* __restrict__ kg,
                                                 const u16* __restrict__ vtg, u16* __restrict__ attnb)
{
    __shared__ u16 Ks[64*72];
    __shared__ u16 Vts[64*72];
    __shared__ u16 Ps[128*72];

    const float SCL = 0.18033688011112042f;  // (1/sqrt(64)) * log2(e)

    int tid = threadIdx.x;
    int lane = tid & 63;
    int w = tid >> 6;          // wave 0..3 -> q rows w*32..w*32+31
    int lm = lane & 15;
    int lq = lane >> 4;        // quad 0..3
    int qt = (int)(gridDim.x - 1) - (int)blockIdx.x;   // heavy tiles first
    int bh = blockIdx.y;
    int b_ = bh >> 4, h_ = bh & 15;
    int q0 = qt * 128;

    const size_t basek  = (size_t)bh * TT * DD;
    const size_t basevt = (size_t)bh * DD * TT;

    // Q fragments resident in registers: aq[i][ks] = Q[q0+w*32+i*16+lm][ks*32+lq*8 ..+7]
    short8 aq[2][2];
    {
        const u16* qbase = qg + basek + (size_t)(q0 + w*32 + lm) * DD + lq*8;
#pragma unroll
        for (int i = 0; i < 2; ++i)
#pragma unroll
            for (int ks = 0; ks < 2; ++ks)
                aq[i][ks] = *(const short8*)(qbase + i*16*DD + ks*32);
    }

    floatx4 oacc[2][4];
#pragma unroll
    for (int i = 0; i < 2; ++i)
#pragma unroll
        for (int j = 0; j < 4; ++j)
            oacc[i][j] = (floatx4){0.f, 0.f, 0.f, 0.f};
    float mrun[2][4], lrun[2][4];
#pragma unroll
    for (int i = 0; i < 2; ++i)
#pragma unroll
        for (int r = 0; r < 4; ++r) { mrun[i][r] = -3e38f; lrun[i][r] = 0.f; }

    short8 ones;
#pragma unroll
    for (int j = 0; j < 8; ++j) ones[j] = (short)0x3F80;  // bf16 1.0

    // staging addresses: thread t handles row t>>2 (0..63), 16 cols at (t&3)*16
    int srow = tid >> 2;
    int scol = (tid & 3) * 16;
    const u16* kgsrc  = kg  + basek  + (size_t)srow * DD + scol;
    const u16* vtsrc  = vtg + basevt + (size_t)srow * TT + scol;
    u16* ksdst  = Ks  + srow*72 + scol;
    u16* vtdst  = Vts + srow*72 + scol;

    int nkt = 2*qt + 2;
    int wrowmax = q0 + w*32 + 31;

    for (int kt = 0; kt < nkt; ++kt) {
        // prefetch global before the barrier (overlaps previous compute)
        uint4 k0v = *(const uint4*)(kgsrc + (size_t)kt*64*DD);
        uint4 k1v = *(const uint4*)(kgsrc + (size_t)kt*64*DD + 8);
        uint4 v0v = *(const uint4*)(vtsrc + kt*64);
        uint4 v1v = *(const uint4*)(vtsrc + kt*64 + 8);
        __syncthreads();   // previous iteration's LDS reads complete
        *(uint4*)ksdst       = k0v;
        *(uint4*)(ksdst + 8) = k1v;
        *(uint4*)vtdst       = v0v;
        *(uint4*)(vtdst + 8) = v1v;
        __syncthreads();

        if (kt*64 <= wrowmax) {   // wave-uniform: skip fully-masked tiles
            // ---- S = Q K^T ----
            floatx4 s[2][4];
#pragma unroll
            for (int i = 0; i < 2; ++i)
#pragma unroll
                for (int jn = 0; jn < 4; ++jn)
                    s[i][jn] = (floatx4){0.f, 0.f, 0.f, 0.f};
#pragma unroll
            for (int jn = 0; jn < 4; ++jn) {
                short8 bk0 = *(const short8*)&Ks[(jn*16 + lm)*72 + lq*8];
                short8 bk1 = *(const short8*)&Ks[(jn*16 + lm)*72 + 32 + lq*8];
#pragma unroll
                for (int i = 0; i < 2; ++i) {
                    s[i][jn] = __builtin_amdgcn_mfma_f32_16x16x32_bf16(aq[i][0], bk0, s[i][jn], 0, 0, 0);
                    s[i][jn] = __builtin_amdgcn_mfma_f32_16x16x32_bf16(aq[i][1], bk1, s[i][jn], 0, 0, 0);
                }
            }

            // ---- scale + causal mask + online softmax (registers) ----
            float alpha[2][4];
#pragma unroll
            for (int i = 0; i < 2; ++i) {
                bool needmask = (kt*64 + 63) > (q0 + w*32 + i*16);
#pragma unroll
                for (int jn = 0; jn < 4; ++jn) {
#pragma unroll
                    for (int r = 0; r < 4; ++r) {
                        float z = s[i][jn][r] * SCL;
                        if (needmask) {
                            int col = kt*64 + jn*16 + lm;
                            int row = q0 + w*32 + i*16 + lq*4 + r;
                            if (col > row) z = -3e38f;
                        }
                        s[i][jn][r] = z;
                    }
                }
#pragma unroll
                for (int r = 0; r < 4; ++r) {
                    float tmax = fmaxf(fmaxf(s[i][0][r], s[i][1][r]), fmaxf(s[i][2][r], s[i][3][r]));
                    tmax = dpp_rowmax16(tmax);
                    float newm = fmaxf(mrun[i][r], tmax);
                    alpha[i][r] = exp2f(mrun[i][r] - newm);
                    mrun[i][r] = newm;
                    int prow = (w*32 + i*16 + lq*4 + r)*72;
#pragma unroll
                    for (int jn = 0; jn < 4; ++jn) {
                        float p = exp2f(s[i][jn][r] - newm);
                        Ps[prow + jn*16 + lm] = f2bf(p);
                    }
                }
            }

            // ---- P (LDS round-trip) -> A-frags; row-sum via ones-MFMA; PV ----
            short8 ap[2][2];
#pragma unroll
            for (int i = 0; i < 2; ++i)
#pragma unroll
                for (int ks = 0; ks < 2; ++ks)
                    ap[i][ks] = *(const short8*)&Ps[(w*32 + i*16 + lm)*72 + ks*32 + lq*8];

            floatx4 ls[2];
#pragma unroll
            for (int i = 0; i < 2; ++i) {
                ls[i] = (floatx4){0.f, 0.f, 0.f, 0.f};
                ls[i] = __builtin_amdgcn_mfma_f32_16x16x32_bf16(ap[i][0], ones, ls[i], 0, 0, 0);
                ls[i] = __builtin_amdgcn_mfma_f32_16x16x32_bf16(ap[i][1], ones, ls[i], 0, 0, 0);
            }
#pragma unroll
            for (int i = 0; i < 2; ++i)
#pragma unroll
                for (int r = 0; r < 4; ++r)
                    lrun[i][r] = lrun[i][r]*alpha[i][r] + ls[i][r];

#pragma unroll
            for (int i = 0; i < 2; ++i)
#pragma unroll
                for (int jd = 0; jd < 4; ++jd)
#pragma unroll
                    for (int r = 0; r < 4; ++r)
                        oacc[i][jd][r] *= alpha[i][r];

#pragma unroll
            for (int jd = 0; jd < 4; ++jd) {
                short8 bv0 = *(const short8*)&Vts[(jd*16 + lm)*72 + lq*8];
                short8 bv1 = *(const short8*)&Vts[(jd*16 + lm)*72 + 32 + lq*8];
#pragma unroll
                for (int i = 0; i < 2; ++i) {
                    oacc[i][jd] = __builtin_amdgcn_mfma_f32_16x16x32_bf16(ap[i][0], bv0, oacc[i][jd], 0, 0, 0);
                    oacc[i][jd] = __builtin_amdgcn_mfma_f32_16x16x32_bf16(ap[i][1], bv1, oacc[i][jd], 0, 0, 0);
                }
            }
        }
    }

    // ---- epilogue: O / l -> attnb [B,T,C] bf16 ----
#pragma unroll
    for (int i = 0; i < 2; ++i) {
#pragma unroll
        for (int r = 0; r < 4; ++r) {
            float invl = 1.f / lrun[i][r];
            int row = q0 + w*32 + i*16 + lq*4 + r;
            u16* orow = attnb + ((size_t)(b_*TT + row)) * CC + h_*DD + lm;
#pragma unroll
            for (int jd = 0; jd < 4; ++jd)
                orow[jd*16] = f2bf(oacc[i][jd][r] * invl);
        }
    }
}

extern "C" void kernel_launch(void* const* d_in, const int* in_sizes, int n_in,
                              void* d_out, int out_size, void* d_ws, size_t ws_size,
                              hipStream_t stream)
{
    const float* x  = (const float*)d_in[0];
    const float* Wq = (const float*)d_in[1];
    const float* bq = (const float*)d_in[2];
    const float* Wk = (const float*)d_in[3];
    const float* bk = (const float*)d_in[4];
    const float* Wv = (const float*)d_in[5];
    const float* bv = (const float*)d_in[6];
    const float* Wo = (const float*)d_in[7];
    const float* bo = (const float*)d_in[8];
    float* out = (float*)d_out;

    char* ws = (char*)d_ws;
    u16* xb   = (u16*)(ws);                      // 0..8M: xb (then reused as attnb)
    u16* wqb  = (u16*)(ws + (size_t)( 8<<20));
    u16* wkb  = (u16*)(ws + (size_t)(10<<20));
    u16* wvb  = (u16*)(ws + (size_t)(12<<20));
    u16* wob  = (u16*)(ws + (size_t)(14<<20));
    u16* q    = (u16*)(ws + (size_t)(16<<20));   // [B,H,T,D]
    u16* k    = (u16*)(ws + (size_t)(24<<20));   // [B,H,T,D]
    u16* v    = (u16*)(ws + (size_t)(32<<20));   // [B,H,T,D]
    u16* vt   = (u16*)(ws + (size_t)(40<<20));   // [B,H,D,T]
    u16* attnb = xb;                             // xb dead after qkv_gemm

    cast_kernel<<<dim3(MM*CC/4/256), dim3(256), 0, stream>>>(x,  xb,  MM*CC/4);
    cast_kernel<<<dim3(CC*CC/4/256), dim3(256), 0, stream>>>(Wq, wqb, CC*CC/4);
    cast_kernel<<<dim3(CC*CC/4/256), dim3(256), 0, stream>>>(Wk, wkb, CC*CC/4);
    cast_kernel<<<dim3(CC*CC/4/256), dim3(256), 0, stream>>>(Wv, wvb, CC*CC/4);
    cast_kernel<<<dim3(CC*CC/4/256), dim3(256), 0, stream>>>(Wo, wob, CC*CC/4);

    dim3 gq(CC/128, MM/128, 3);
    qkv_gemm<<<gq, dim3(256), 0, stream>>>(xb, wqb, wkb, wvb, bq, bk, bv, q, k, v);

    transpose_v<<<dim3(TT/64, BBATCH*HH), dim3(256), 0, stream>>>(v, vt);

    attn_mfma<<<dim3(TT/128, BBATCH*HH), dim3(256), 0, stream>>>(q, k, vt, attnb);

    dim3 go(CC/128, MM/128);
    o_gemm<<<go, dim3(256), 0, stream>>>(attnb, wob, bo, out);
}

// Round 3
// 219.003 us; speedup vs baseline: 3.5873x; 1.3244x over previous
//
#include <hip/hip_runtime.h>
#include <hip/hip_bf16.h>

using u16 = unsigned short;
using u32 = unsigned int;
using short8  = __attribute__((ext_vector_type(8))) short;
using short4v = __attribute__((ext_vector_type(4))) short;
using floatx4 = __attribute__((ext_vector_type(4))) float;

#define TT 2048
#define CC 1024
#define HH 16
#define DD 64
#define BBATCH 2
#define MM (BBATCH*TT)   // 4096

// (1/sqrt(64)) * log2(e): folded into Q at projection epilogue; softmax uses exp2.
#define QSCALE 0.18033688011112042f

__device__ __forceinline__ u16 f2bf(float f) {
    u32 u = __float_as_uint(f);
    u += 0x7fffu + ((u >> 16) & 1u);   // RNE
    return (u16)(u >> 16);
}
__device__ __forceinline__ float bf2f(u16 s) {
    return __uint_as_float(((u32)s) << 16);
}
__device__ __forceinline__ float bpermf(float v, int srclane) {
    return __int_as_float(__builtin_amdgcn_ds_bpermute(srclane * 4, __float_as_int(v)));
}
// async global->LDS, 16B per lane (m97 pattern)
__device__ __forceinline__ void gll16(const u16* g, u16* l) {
    __builtin_amdgcn_global_load_lds((const __attribute__((address_space(1))) void*)g,
                                     (__attribute__((address_space(3))) void*)l, 16, 0, 0);
}

// ---------------- fused cast fp32 -> bf16 (x + 4 weights, one launch) ----------------
__global__ __launch_bounds__(256) void cast_all(const float* __restrict__ x,
    const float* __restrict__ Wq, const float* __restrict__ Wk,
    const float* __restrict__ Wv, const float* __restrict__ Wo,
    u16* __restrict__ xb, u16* __restrict__ wqb, u16* __restrict__ wkb,
    u16* __restrict__ wvb, u16* __restrict__ wob)
{
    int i = blockIdx.x * 256 + threadIdx.x;   // 0 .. 2097151
    const float* src; u16* dst; int off;
    if (i < 1048576) { src = x; dst = xb; off = i; }
    else {
        int j = i - 1048576;
        int s = j >> 18;           // 0..3
        off = j & 262143;
        src = (s == 0) ? Wq : (s == 1) ? Wk : (s == 2) ? Wv : Wo;
        dst = (s == 0) ? wqb : (s == 1) ? wkb : (s == 2) ? wvb : wob;
    }
    float4 v = ((const float4*)src)[off];
    u16 r[4];
    r[0] = f2bf(v.x); r[1] = f2bf(v.y); r[2] = f2bf(v.z); r[3] = f2bf(v.w);
    ((ushort4*)dst)[off] = *(ushort4*)r;
}

// ---------------- V transpose: [BH][T][D] -> [BH][D][T] ----------------
__global__ __launch_bounds__(256) void transpose_v(const u16* __restrict__ v, u16* __restrict__ vt) {
    __shared__ u16 tile[64][72];
    int bh = blockIdx.y;
    int t0 = blockIdx.x * 64;
    int r = threadIdx.x >> 2;
    int c = (threadIdx.x & 3) * 16;
    const u16* src = v + ((size_t)bh * TT + t0 + r) * DD + c;
    *(uint4*)&tile[r][c]     = *(const uint4*)src;
    *(uint4*)&tile[r][c + 8] = *(const uint4*)(src + 8);
    __syncthreads();
    u16 tmp[16];
#pragma unroll
    for (int j = 0; j < 16; ++j) tmp[j] = tile[c + j][r];
    u16* dst = vt + ((size_t)bh * DD + r) * TT + t0 + c;
    *(uint4*)dst       = *(uint4*)&tmp[0];
    *(uint4*)(dst + 8) = *(uint4*)&tmp[8];
}

// ---------------- bf16 MFMA GEMM (m97-style global_load_lds staging): y = (A @ W^T + b)*scale ----------------
template <int OUT_MODE>
__device__ __forceinline__ void gemm_core(const u16* __restrict__ A, const u16* __restrict__ W,
                                          const float* __restrict__ bias, float outscale,
                                          void* __restrict__ outp)
{
    __shared__ u16 As[128*32];
    __shared__ u16 Bs[128*32];
    const int K = CC;
    int tid = threadIdx.x;
    int m0 = blockIdx.y * 128;
    int n0 = blockIdx.x * 128;
    int lane = tid & 63;
    int w  = tid >> 6;
    int wm = (w >> 1) * 64;
    int wn = (w & 1) * 64;
    int lm = lane & 15;
    int lq = lane >> 4;

    floatx4 acc[4][4];
#pragma unroll
    for (int i = 0; i < 4; ++i)
#pragma unroll
        for (int j = 0; j < 4; ++j)
            acc[i][j] = (floatx4){0.f, 0.f, 0.f, 0.f};

    const u16* ag = A + (size_t)(m0 + (tid >> 2)) * K + (tid & 3) * 8;
    const u16* wg = W + (size_t)(n0 + (tid >> 2)) * K + (tid & 3) * 8;
    u16* asl = As + tid * 8;     // lane-contiguous 16B: wave-uniform base + lane*16
    u16* bsl = Bs + tid * 8;

    for (int k0 = 0; k0 < K; k0 += 32) {
        __syncthreads();
        gll16(ag + k0,           asl);
        gll16(ag + 64*K + k0,    asl + 2048);
        gll16(wg + k0,           bsl);
        gll16(wg + 64*K + k0,    bsl + 2048);
        __syncthreads();
        short8 af[4], bfr[4];
#pragma unroll
        for (int t = 0; t < 4; ++t) {
            af[t]  = *(const short8*)(As + (wm + t*16 + lm)*32 + lq*8);
            bfr[t] = *(const short8*)(Bs + (wn + t*16 + lm)*32 + lq*8);
        }
#pragma unroll
        for (int i = 0; i < 4; ++i)
#pragma unroll
            for (int j = 0; j < 4; ++j)
                acc[i][j] = __builtin_amdgcn_mfma_f32_16x16x32_bf16(af[i], bfr[j], acc[i][j], 0, 0, 0);
    }

#pragma unroll
    for (int j = 0; j < 4; ++j) {
        int col = n0 + wn + j*16 + lm;
        float bv = bias[col];
#pragma unroll
        for (int i = 0; i < 4; ++i) {
#pragma unroll
            for (int r = 0; r < 4; ++r) {
                int row = m0 + wm + i*16 + lq*4 + r;
                float val = (acc[i][j][r] + bv) * outscale;
                if (OUT_MODE == 0) {
                    int b_ = row >> 11, t_ = row & (TT-1);
                    int h_ = col >> 6,  d_ = col & 63;
                    ((u16*)outp)[(((size_t)(b_*HH + h_) * TT + t_) * DD) + d_] = f2bf(val);
                } else {
                    ((float*)outp)[(size_t)row * CC + col] = val;
                }
            }
        }
    }
}

__global__ __launch_bounds__(256, 2) void qkv_gemm(const u16* __restrict__ xb,
    const u16* __restrict__ wq, const u16* __restrict__ wk, const u16* __restrict__ wv,
    const float* __restrict__ bq, const float* __restrict__ bk, const float* __restrict__ bv,
    u16* __restrict__ q, u16* __restrict__ k, u16* __restrict__ v)
{
    int z = blockIdx.z;
    const u16* W = (z == 0) ? wq : (z == 1) ? wk : wv;
    const float* bias = (z == 0) ? bq : (z == 1) ? bk : bv;
    u16* outp = (z == 0) ? q : (z == 1) ? k : v;
    float scl = (z == 0) ? QSCALE : 1.0f;   // fold softmax scale (log2 domain) into Q
    gemm_core<0>(xb, W, bias, scl, outp);
}

__global__ __launch_bounds__(256, 2) void o_gemm(const u16* __restrict__ a, const u16* __restrict__ w,
                                                 const float* __restrict__ bias, float* __restrict__ outp)
{
    gemm_core<1>(a, w, bias, 1.0f, outp);
}

// ---------------- MFMA flash attention, causal, no P round-trip ----------------
// Computes S^T = K·Q^T so P lands in registers in exactly the A-operand layout
// of v_mfma_f32_16x16x16_bf16 (keys at lq*4+j). q: pre-scaled bf16 [BH][T][D];
// k: [BH][T][D]; vt: [BH][D][T]; attnb: [B][T][C] bf16.
// Br=128 (4 waves x 32 q-rows), Bc=64.
__global__ __launch_bounds__(256, 2) void attn_mfma(const u16* __restrict__ qg, const u16* __restrict__ kg,
                                                    const u16* __restrict__ vtg, u16* __restrict__ attnb)
{
    __shared__ u16 Ks[64*72];
    __shared__ u16 Vs[64*72];   // kb-swizzled: col = (kb>>1)*32 + lq*8 + (kb&1)*4 + j

    int tid = threadIdx.x;
    int lane = tid & 63;
    int w = tid >> 6;
    int lm = lane & 15;
    int lq = lane >> 4;
    int qt = (int)(gridDim.x - 1) - (int)blockIdx.x;   // heavy tiles first
    int bh = blockIdx.y;
    int b_ = bh >> 4, h_ = bh & 15;
    int q0 = qt * 128;

    const size_t basek  = (size_t)bh * TT * DD;
    const size_t basevt = (size_t)bh * DD * TT;

    // Q fragments (B-operand for S^T): aq[i][ks] = Q[q0+w*32+i*16+lm][ks*32+lq*8 ..+7]
    short8 aq[2][2];
    {
        const u16* qbase = qg + basek + (size_t)(q0 + w*32 + lm) * DD + lq*8;
#pragma unroll
        for (int i = 0; i < 2; ++i)
#pragma unroll
            for (int ks = 0; ks < 2; ++ks)
                aq[i][ks] = *(const short8*)(qbase + i*16*DD + ks*32);
    }

    floatx4 oacc[2][4];
#pragma unroll
    for (int i = 0; i < 2; ++i)
#pragma unroll
        for (int j = 0; j < 4; ++j)
            oacc[i][j] = (floatx4){0.f, 0.f, 0.f, 0.f};
    float mrun[2] = {-3e38f, -3e38f};
    float lrun[2] = {0.f, 0.f};

    // staging: thread t stages row t>>2 (0..63), 16 cols at (t&3)*16
    int srow = tid >> 2;
    int kb   = tid & 3;
    int p_   = kb >> 1, kb01 = kb & 1;
    const u16* ksrc = kg  + basek  + (size_t)srow * DD + kb*16;
    const u16* vsrc = vtg + basevt + (size_t)srow * TT + kb*16;
    u16* kdst = Ks + srow*72 + kb*16;
    u16* vdst = Vs + srow*72 + p_*32 + kb01*4;

    int nkt = 2*qt + 2;
    int wrowmax = q0 + w*32 + 31;

    for (int kt = 0; kt < nkt; ++kt) {
        uint4 k0v = *(const uint4*)(ksrc + (size_t)kt*64*DD);
        uint4 k1v = *(const uint4*)(ksrc + (size_t)kt*64*DD + 8);
        uint4 v0v = *(const uint4*)(vsrc + kt*64);
        uint4 v1v = *(const uint4*)(vsrc + kt*64 + 8);
        __syncthreads();
        *(uint4*)kdst       = k0v;
        *(uint4*)(kdst + 8) = k1v;
        *(uint2*)(vdst)      = make_uint2(v0v.x, v0v.y);   // t_local kb*16+0..3
        *(uint2*)(vdst + 8)  = make_uint2(v0v.z, v0v.w);   // +4..7
        *(uint2*)(vdst + 16) = make_uint2(v1v.x, v1v.y);   // +8..11
        *(uint2*)(vdst + 24) = make_uint2(v1v.z, v1v.w);   // +12..15
        __syncthreads();

        if (kt*64 <= wrowmax) {
            // ---- S^T = K Q^T : C/D col=lm -> q, row=lq*4+r -> key ----
            floatx4 st[2][4];
#pragma unroll
            for (int i = 0; i < 2; ++i)
#pragma unroll
                for (int jn = 0; jn < 4; ++jn)
                    st[i][jn] = (floatx4){0.f, 0.f, 0.f, 0.f};
#pragma unroll
            for (int jn = 0; jn < 4; ++jn) {
                short8 kf0 = *(const short8*)&Ks[(jn*16 + lm)*72 + lq*8];
                short8 kf1 = *(const short8*)&Ks[(jn*16 + lm)*72 + 32 + lq*8];
#pragma unroll
                for (int i = 0; i < 2; ++i) {
                    st[i][jn] = __builtin_amdgcn_mfma_f32_16x16x32_bf16(kf0, aq[i][0], st[i][jn], 0, 0, 0);
                    st[i][jn] = __builtin_amdgcn_mfma_f32_16x16x32_bf16(kf1, aq[i][1], st[i][jn], 0, 0, 0);
                }
            }

            int kbase = kt*64;
            short4v ap[2][4];
#pragma unroll
            for (int i = 0; i < 2; ++i) {
                int qrow = q0 + w*32 + i*16 + lm;   // this lane's single q row
                // causal mask (wave-uniform branch)
                if (kbase + 63 > q0 + w*32 + i*16) {
#pragma unroll
                    for (int jn = 0; jn < 4; ++jn)
#pragma unroll
                        for (int r = 0; r < 4; ++r) {
                            int key = kbase + jn*16 + lq*4 + r;
                            if (key > qrow) st[i][jn][r] = -__builtin_inff();
                        }
                }
                // row max: in-lane over 16, then across quads
                float mx = st[i][0][0];
#pragma unroll
                for (int jn = 0; jn < 4; ++jn)
#pragma unroll
                    for (int r = 0; r < 4; ++r) mx = fmaxf(mx, st[i][jn][r]);
                mx = fmaxf(mx, __shfl_xor(mx, 16));
                mx = fmaxf(mx, __shfl_xor(mx, 32));
                float mold = mrun[i];
                float newm = fmaxf(mold, mx);
                mrun[i] = newm;
                float psum = 0.f;
#pragma unroll
                for (int jn = 0; jn < 4; ++jn)
#pragma unroll
                    for (int r = 0; r < 4; ++r) {
                        float pe = __builtin_amdgcn_exp2f(st[i][jn][r] - newm);
                        st[i][jn][r] = pe;
                        psum += pe;
                    }
                psum += __shfl_xor(psum, 16);
                psum += __shfl_xor(psum, 32);
                float alpha = __builtin_amdgcn_exp2f(mold - newm);
                lrun[i] = lrun[i]*alpha + psum;
                // pack P -> A-frags (truncate to bf16): reg j = key lq*4+j
#pragma unroll
                for (int jn = 0; jn < 4; ++jn) {
                    u32 lo = __builtin_amdgcn_perm(__float_as_uint(st[i][jn][1]),
                                                   __float_as_uint(st[i][jn][0]), 0x07060302u);
                    u32 hi = __builtin_amdgcn_perm(__float_as_uint(st[i][jn][3]),
                                                   __float_as_uint(st[i][jn][2]), 0x07060302u);
                    uint2 pk = make_uint2(lo, hi);
                    ap[i][jn] = __builtin_bit_cast(short4v, pk);
                }
                // rescale O only if the max actually moved somewhere in the wave
                if (__ballot(newm != mold)) {
                    float ar[4];
#pragma unroll
                    for (int r = 0; r < 4; ++r) ar[r] = bpermf(alpha, lq*4 + r);
#pragma unroll
                    for (int jd = 0; jd < 4; ++jd)
#pragma unroll
                        for (int r = 0; r < 4; ++r) oacc[i][jd][r] *= ar[r];
                }
            }

            // ---- O += P V via 16x16x16 (A=P from regs, B=V^T swizzled LDS) ----
#pragma unroll
            for (int p2 = 0; p2 < 2; ++p2) {
#pragma unroll
                for (int jd = 0; jd < 4; ++jd) {
                    short8 vb = *(const short8*)&Vs[(jd*16 + lm)*72 + p2*32 + lq*8];
                    short4v blo, bhi;
#pragma unroll
                    for (int j = 0; j < 4; ++j) { blo[j] = vb[j]; bhi[j] = vb[j+4]; }
#pragma unroll
                    for (int i = 0; i < 2; ++i) {
                        oacc[i][jd] = __builtin_amdgcn_mfma_f32_16x16x16bf16_1k(ap[i][2*p2],   blo, oacc[i][jd], 0, 0, 0);
                        oacc[i][jd] = __builtin_amdgcn_mfma_f32_16x16x16bf16_1k(ap[i][2*p2+1], bhi, oacc[i][jd], 0, 0, 0);
                    }
                }
            }
        }
    }

    // ---- epilogue: O / l -> attnb [B,T,C] bf16 (O rows = lq*4+r, cols d = jd*16+lm) ----
#pragma unroll
    for (int i = 0; i < 2; ++i) {
        float il[4];
#pragma unroll
        for (int r = 0; r < 4; ++r) il[r] = 1.f / bpermf(lrun[i], lq*4 + r);
#pragma unroll
        for (int r = 0; r < 4; ++r) {
            int qrow = q0 + w*32 + i*16 + lq*4 + r;
            u16* orow = attnb + ((size_t)(b_*TT + qrow)) * CC + h_*DD + lm;
#pragma unroll
            for (int jd = 0; jd < 4; ++jd)
                orow[jd*16] = f2bf(oacc[i][jd][r] * il[r]);
        }
    }
}

extern "C" void kernel_launch(void* const* d_in, const int* in_sizes, int n_in,
                              void* d_out, int out_size, void* d_ws, size_t ws_size,
                              hipStream_t stream)
{
    const float* x  = (const float*)d_in[0];
    const float* Wq = (const float*)d_in[1];
    const float* bq = (const float*)d_in[2];
    const float* Wk = (const float*)d_in[3];
    const float* bk = (const float*)d_in[4];
    const float* Wv = (const float*)d_in[5];
    const float* bv = (const float*)d_in[6];
    const float* Wo = (const float*)d_in[7];
    const float* bo = (const float*)d_in[8];
    float* out = (float*)d_out;

    char* ws = (char*)d_ws;
    u16* xb   = (u16*)(ws);                      // 8 MB (reused as attnb)
    u16* wqb  = (u16*)(ws + (size_t)( 8<<20));
    u16* wkb  = (u16*)(ws + (size_t)(10<<20));
    u16* wvb  = (u16*)(ws + (size_t)(12<<20));
    u16* wob  = (u16*)(ws + (size_t)(14<<20));
    u16* q    = (u16*)(ws + (size_t)(16<<20));   // [B,H,T,D], pre-scaled
    u16* k    = (u16*)(ws + (size_t)(24<<20));   // [B,H,T,D]
    u16* v    = (u16*)(ws + (size_t)(32<<20));   // [B,H,T,D]
    u16* vt   = (u16*)(ws + (size_t)(40<<20));   // [B,H,D,T]
    u16* attnb = xb;                             // xb dead after qkv_gemm

    cast_all<<<dim3(8192), dim3(256), 0, stream>>>(x, Wq, Wk, Wv, Wo, xb, wqb, wkb, wvb, wob);

    dim3 gq(CC/128, MM/128, 3);
    qkv_gemm<<<gq, dim3(256), 0, stream>>>(xb, wqb, wkb, wvb, bq, bk, bv, q, k, v);

    transpose_v<<<dim3(TT/64, BBATCH*HH), dim3(256), 0, stream>>>(v, vt);

    attn_mfma<<<dim3(TT/128, BBATCH*HH), dim3(256), 0, stream>>>(q, k, vt, attnb);

    dim3 go(CC/128, MM/128);
    o_gemm<<<go, dim3(256), 0, stream>>>(attnb, wob, bo, out);
}